// Round 1
// baseline (73.969 us; speedup 1.0000x reference)
//
#include <hip/hip_runtime.h>
#include <math.h>

// Problem geometry (fixed by setup_inputs): N=64, C=128, H=W=56
#define NBATCH 64
#define NCHAN  128
#define HWSZ   3136          // 56*56
#define HW4    784           // HWSZ/4
#define NHW    200704        // NBATCH*HWSZ (elements per channel)
#define TOTAL4 6422528       // N*C*HW/4 float4s

constexpr float EPS_  = 1e-5f;
constexpr float MOM_  = 0.1f;

// AP2(x) = sign(x) * 2^round(log2|x|), round-half-to-even (matches jnp.round)
__device__ __forceinline__ float ap2(float v) {
    float a = fabsf(v);
    float p = exp2f(rintf(__log2f(a) == __log2f(a) ? log2f(a) : log2f(a)));
    // (use precise log2f; the ternary above is redundant but keeps precise call)
    return copysignf(p, v);
}

__device__ __forceinline__ float ap2_precise(float v) {
    float a = fabsf(v);
    float p = exp2f(rintf(log2f(a)));   // log2f(0) = -inf -> exp2f(-inf) = 0
    return copysignf(p, v);
}

// Block (256 threads = 4 waves of 64) sum reduction; result valid on thread 0.
__device__ __forceinline__ float block_reduce_sum(float v) {
    #pragma unroll
    for (int off = 32; off > 0; off >>= 1) v += __shfl_down(v, off, 64);
    __shared__ float s[4];
    const int lane = threadIdx.x & 63;
    const int w    = threadIdx.x >> 6;
    if (lane == 0) s[w] = v;
    __syncthreads();
    if (threadIdx.x == 0) v = (s[0] + s[1]) + (s[2] + s[3]);
    return v;
}

// K1: per-(n,c)-slice sum of x -> part[c*NBATCH + n]
__global__ void k_mean_partial(const float* __restrict__ x,
                               float* __restrict__ part) {
    const int b = blockIdx.x;          // b = n*NCHAN + c
    const int n = b >> 7;              // / 128
    const int c = b & 127;
    const float4* xp = (const float4*)(x + (size_t)b * HWSZ);
    float s = 0.f;
    for (int i = threadIdx.x; i < HW4; i += 256) {
        float4 v = xp[i];
        s += (v.x + v.y) + (v.z + v.w);
    }
    s = block_reduce_sum(s);
    if (threadIdx.x == 0) part[c * NBATCH + n] = s;
}

// K2: finalize rm[c] = 0.9*running_mean + 0.1*mean
__global__ void k_finalize_mean(const float* __restrict__ part,
                                const float* __restrict__ rmean,
                                float* __restrict__ rm_out) {
    const int c = threadIdx.x;         // 128 threads
    float s = 0.f;
    #pragma unroll 8
    for (int n = 0; n < NBATCH; ++n) s += part[c * NBATCH + n];
    const float bm = s / (float)NHW;
    rm_out[c] = (1.f - MOM_) * rmean[c] + MOM_ * bm;
}

// K3: per-(n,c)-slice sum of centered*AP2(centered)
__global__ void k_var_partial(const float* __restrict__ x,
                              const float* __restrict__ rm,
                              float* __restrict__ part) {
    const int b = blockIdx.x;
    const int n = b >> 7;
    const int c = b & 127;
    const float m = rm[c];
    const float4* xp = (const float4*)(x + (size_t)b * HWSZ);
    float s = 0.f;
    for (int i = threadIdx.x; i < HW4; i += 256) {
        float4 v = xp[i];
        float c0 = v.x - m, c1 = v.y - m, c2 = v.z - m, c3 = v.w - m;
        s += c0 * ap2_precise(c0);
        s += c1 * ap2_precise(c1);
        s += c2 * ap2_precise(c2);
        s += c3 * ap2_precise(c3);
    }
    s = block_reduce_sum(s);
    if (threadIdx.x == 0) part[c * NBATCH + n] = s;
}

// K4: finalize scale[c] = AP2(weight[c]) * AP2(1/sqrt(rv+eps))
__global__ void k_finalize_var(const float* __restrict__ part,
                               const float* __restrict__ rvar,
                               const float* __restrict__ weight,
                               float* __restrict__ scale_out) {
    const int c = threadIdx.x;         // 128 threads
    float s = 0.f;
    #pragma unroll 8
    for (int n = 0; n < NBATCH; ++n) s += part[c * NBATCH + n];
    const float bv = s / (float)NHW;
    const float rv = (1.f - MOM_) * rvar[c] + MOM_ * bv;
    const float inv_std = ap2_precise(1.0f / sqrtf(rv + EPS_));
    scale_out[c] = ap2_precise(weight[c]) * inv_std;   // product of powers of 2: exact
}

// K5: out = scale[c]*(x - rm[c]) + bias[c], one float4 per thread
__global__ void k_output(const float* __restrict__ x,
                         const float* __restrict__ rm,
                         const float* __restrict__ scale,
                         const float* __restrict__ bias,
                         float* __restrict__ out) {
    const unsigned i4 = blockIdx.x * 256u + threadIdx.x;
    const unsigned c  = (i4 / HW4) & 127u;   // slice index % C
    const float m  = rm[c];
    const float sc = scale[c];
    const float bb = bias[c];
    float4 v = ((const float4*)x)[i4];
    float4 o;
    o.x = fmaf(sc, v.x - m, bb);
    o.y = fmaf(sc, v.y - m, bb);
    o.z = fmaf(sc, v.z - m, bb);
    o.w = fmaf(sc, v.w - m, bb);
    ((float4*)out)[i4] = o;
}

extern "C" void kernel_launch(void* const* d_in, const int* in_sizes, int n_in,
                              void* d_out, int out_size, void* d_ws, size_t ws_size,
                              hipStream_t stream) {
    const float* x      = (const float*)d_in[0];
    const float* weight = (const float*)d_in[1];
    const float* bias   = (const float*)d_in[2];
    const float* rmean  = (const float*)d_in[3];
    const float* rvar   = (const float*)d_in[4];
    float* out = (float*)d_out;

    float* ws        = (float*)d_ws;
    float* part_mean = ws;                 // 8192 floats
    float* part_var  = ws + 8192;          // 8192 floats
    float* rm        = ws + 16384;         // 128
    float* scale     = ws + 16512;         // 128

    const int nslices = NBATCH * NCHAN;    // 8192

    k_mean_partial<<<nslices, 256, 0, stream>>>(x, part_mean);
    k_finalize_mean<<<1, NCHAN, 0, stream>>>(part_mean, rmean, rm);
    k_var_partial<<<nslices, 256, 0, stream>>>(x, rm, part_var);
    k_finalize_var<<<1, NCHAN, 0, stream>>>(part_var, rvar, weight, scale);
    k_output<<<TOTAL4 / 256, 256, 0, stream>>>(x, rm, scale, bias, out);
}

// Round 3
// 72.118 us; speedup vs baseline: 1.0257x; 1.0257x over previous
//
#include <hip/hip_runtime.h>
#include <math.h>

// Problem geometry (fixed by setup_inputs): N=64, C=128, H=W=56
#define NBATCH 64
#define NCHAN  128
#define HWSZ   3136          // 56*56
#define HW4    784           // HWSZ/4
#define NHW    200704        // NBATCH*HWSZ (elements per channel)

constexpr float EPS_  = 1e-5f;
constexpr float MOM_  = 0.1f;

typedef float f32x4 __attribute__((ext_vector_type(4)));  // native vec for NT store

// AP2(x) = sign(x) * 2^round(log2|x|), round-half-to-even (matches jnp.round).
__device__ __forceinline__ float ap2_precise(float v) {
    float a = fabsf(v);
    float p = exp2f(rintf(log2f(a)));   // log2f(0) = -inf -> exp2f(-inf) = 0
    return copysignf(p, v);
}

// Block (256 threads = 4 waves of 64) sum reduction; result valid on thread 0.
__device__ __forceinline__ float block_reduce_sum(float v) {
    #pragma unroll
    for (int off = 32; off > 0; off >>= 1) v += __shfl_down(v, off, 64);
    __shared__ float s[4];
    const int lane = threadIdx.x & 63;
    const int w    = threadIdx.x >> 6;
    if (lane == 0) s[w] = v;
    __syncthreads();
    if (threadIdx.x == 0) v = (s[0] + s[1]) + (s[2] + s[3]);
    return v;
}

// Sum the 64 per-batch partials for channel c; every lane of every wave gets
// the (bit-identical, deterministic) result. NBATCH == wave size == 64.
__device__ __forceinline__ float reduce_partials64(const float* __restrict__ part,
                                                   int c) {
    const int lane = threadIdx.x & 63;
    float v = part[c * NBATCH + lane];
    #pragma unroll
    for (int off = 32; off > 0; off >>= 1) v += __shfl_down(v, off, 64);
    return __shfl(v, 0, 64);   // broadcast lane 0
}

// K1: per-(n,c)-slice sum of x -> part_mean[c*NBATCH + n]
__global__ void k_mean_partial(const float* __restrict__ x,
                               float* __restrict__ part) {
    const int b = blockIdx.x;          // b = n*NCHAN + c
    const int n = b >> 7;
    const int c = b & 127;
    const float4* xp = (const float4*)(x + (size_t)b * HWSZ);
    float s = 0.f;
    for (int i = threadIdx.x; i < HW4; i += 256) {
        float4 v = xp[i];
        s += (v.x + v.y) + (v.z + v.w);
    }
    s = block_reduce_sum(s);
    if (threadIdx.x == 0) part[c * NBATCH + n] = s;
}

// K2: per-(n,c)-slice sum of centered*AP2(centered); rm finalized inline.
__global__ void k_var_partial(const float* __restrict__ x,
                              const float* __restrict__ part_mean,
                              const float* __restrict__ rmean,
                              float* __restrict__ part_var) {
    const int b = blockIdx.x;
    const int n = b >> 7;
    const int c = b & 127;
    const float msum = reduce_partials64(part_mean, c);
    const float m = (1.f - MOM_) * rmean[c] + MOM_ * (msum / (float)NHW);
    const float4* xp = (const float4*)(x + (size_t)b * HWSZ);
    float s = 0.f;
    for (int i = threadIdx.x; i < HW4; i += 256) {
        float4 v = xp[i];
        float c0 = v.x - m, c1 = v.y - m, c2 = v.z - m, c3 = v.w - m;
        s += c0 * ap2_precise(c0);
        s += c1 * ap2_precise(c1);
        s += c2 * ap2_precise(c2);
        s += c3 * ap2_precise(c3);
    }
    s = block_reduce_sum(s);
    if (threadIdx.x == 0) part_var[c * NBATCH + n] = s;
}

// K3: out = scale[c]*(x - rm[c]) + bias[c]; rm/scale finalized inline
// (block-uniform channel -> scalar ops). Non-temporal stores.
__global__ void k_output(const float* __restrict__ x,
                         const float* __restrict__ part_mean,
                         const float* __restrict__ part_var,
                         const float* __restrict__ rmean,
                         const float* __restrict__ rvar,
                         const float* __restrict__ weight,
                         const float* __restrict__ bias,
                         float* __restrict__ out) {
    const int b = blockIdx.x;
    const int c = b & 127;
    const float msum = reduce_partials64(part_mean, c);
    const float vsum = reduce_partials64(part_var, c);
    const float m  = (1.f - MOM_) * rmean[c] + MOM_ * (msum / (float)NHW);
    const float rv = (1.f - MOM_) * rvar[c]  + MOM_ * (vsum / (float)NHW);
    const float inv_std = ap2_precise(1.0f / sqrtf(rv + EPS_));
    const float sc = ap2_precise(weight[c]) * inv_std;  // powers of 2: exact product
    const float bb = bias[c];
    const float4* xp = (const float4*)(x + (size_t)b * HWSZ);
    f32x4* op = (f32x4*)(out + (size_t)b * HWSZ);
    for (int i = threadIdx.x; i < HW4; i += 256) {
        float4 v = xp[i];
        f32x4 o;
        o.x = fmaf(sc, v.x - m, bb);
        o.y = fmaf(sc, v.y - m, bb);
        o.z = fmaf(sc, v.z - m, bb);
        o.w = fmaf(sc, v.w - m, bb);
        __builtin_nontemporal_store(o, &op[i]);
    }
}

extern "C" void kernel_launch(void* const* d_in, const int* in_sizes, int n_in,
                              void* d_out, int out_size, void* d_ws, size_t ws_size,
                              hipStream_t stream) {
    const float* x      = (const float*)d_in[0];
    const float* weight = (const float*)d_in[1];
    const float* bias   = (const float*)d_in[2];
    const float* rmean  = (const float*)d_in[3];
    const float* rvar   = (const float*)d_in[4];
    float* out = (float*)d_out;

    float* ws        = (float*)d_ws;
    float* part_mean = ws;                 // 8192 floats
    float* part_var  = ws + 8192;          // 8192 floats

    const int nslices = NBATCH * NCHAN;    // 8192

    k_mean_partial<<<nslices, 256, 0, stream>>>(x, part_mean);
    k_var_partial<<<nslices, 256, 0, stream>>>(x, part_mean, rmean, part_var);
    k_output<<<nslices, 256, 0, stream>>>(x, part_mean, part_var,
                                          rmean, rvar, weight, bias, out);
}